// Round 9
// baseline (139.483 us; speedup 1.0000x reference)
//
#include <hip/hip_runtime.h>
#include <hip/hip_bf16.h>
#include <cstdint>

// MCSoftContrastiveLoss, MI355X (gfx950)
// loss = 2 * sum_{i,j} [ log(256) - log( sum_{k,l} sigmoid(2*m_ij*logit) ) ]
//   logit = shift - ns * sqrt(max(x2+y2-2xy,0)+1e-6),  m_ij = +1 if i==j else -1
// R9: 256x256 tile, BK=32, 4-slot rolling LDS pipeline, counted vmcnt(8)
// (loads span barriers, never drained in-loop), 1 barrier/phase, depth-3
// prefetch. Single bf16 GEMM (absmax 0.0 verified R4/R5/R8).

using f32x4 = __attribute__((ext_vector_type(4))) float;
using s16x8 = __attribute__((ext_vector_type(8))) short;

#define DDIM   1024
#define BM     256
#define BN     256
#define BK     32
#define NT     32          // K-tiles = 1024/32
#define LOGKK  5.5451774444795625f
#define DEPS   1e-6f

__device__ __forceinline__ void gload16(const void* g, void* l) {
  __builtin_amdgcn_global_load_lds((const __attribute__((address_space(1))) void*)g,
                                   (__attribute__((address_space(3))) void*)l, 16, 0, 0);
}

__device__ __forceinline__ unsigned short bf16_rne(float x) {
  uint32_t u = __builtin_bit_cast(uint32_t, x);
  uint32_t r = (u + 0x7FFFu + ((u >> 16) & 1u)) >> 16;
  return (unsigned short)r;
}

// -------- prep: 1 wave per row, no barriers, coalesced (R5-verified) --------
__global__ __launch_bounds__(256) void mcsc_prep(
    const float* __restrict__ img, const float* __restrict__ cap,
    unsigned short* __restrict__ Xhi, unsigned short* __restrict__ Yhi,
    float* __restrict__ x2, float* __restrict__ y2, float* __restrict__ out)
{
  int w = blockIdx.x * 4 + (threadIdx.x >> 6);   // 0..8191
  int lane = threadIdx.x & 63;
  int isY = w >> 12;
  int row = w & 4095;
  const float* src = (isY ? cap : img) + (size_t)row * DDIM;
  unsigned short* dst = (isY ? Yhi : Xhi) + (size_t)row * DDIM;

  float s = 0.f;
#pragma unroll
  for (int j = 0; j < 4; ++j) {
    int col = (j * 64 + lane) * 4;
    float4 v = *(const float4*)(src + col);
    const float* vp = (const float*)&v;
    unsigned short h[4];
#pragma unroll
    for (int e = 0; e < 4; ++e) { float x = vp[e]; s += x * x; h[e] = bf16_rne(x); }
    *(ushort4*)(dst + col) = make_ushort4(h[0], h[1], h[2], h[3]);
  }
#pragma unroll
  for (int off = 32; off >= 1; off >>= 1) s += __shfl_xor(s, off);
  if (lane == 0) (isY ? y2 : x2)[row] = s;
  if (w == 0 && lane == 0) out[0] = 0.f;
}

// -------- main: 256x256 NT-GEMM, 4-slot rolling pipeline, fused epilogue --------
__global__ __launch_bounds__(512, 2) void mcsc_main(
    const unsigned short* __restrict__ Xhi, const unsigned short* __restrict__ Yhi,
    const float* __restrict__ x2, const float* __restrict__ y2,
    const float* __restrict__ nsp, const float* __restrict__ shp,
    float* __restrict__ out)
{
  // 4 slots x 32 KB: slot s = [A: 256x32 bf16 (16 KB) | B: 256x32 bf16 (16 KB)]
  // rows are 64 B; swizzle: phys_inrow = logical_kbyte ^ ((row>>1 & 3)<<4)
  __shared__ __align__(16) char lds[4 * 32768];
  __shared__ float redBuf[8];

  // XCD-bijective swizzle (256 % 8 == 0)
  int bid = blockIdx.x;
  int wg = (bid & 7) * 32 + (bid >> 3);
  int bm = wg >> 4, bn = wg & 15;                 // 16 x 16 tile grid
  int rowBase = bm * BM, colBase = bn * BN;

  int t = threadIdx.x;
  int wid = t >> 6, lane = t & 63;
  int lr = lane & 15, lk = lane >> 4;
  int wr = wid >> 2, wc = wid & 3;                // 2M x 4N waves
  int waveRow = wr * 128, waveCol = wc * 64;

  f32x4 acc[8][4] = {};

  // Staging: per slot, per matrix: 2 gload16/thread. Instr i, thread (wid,lane)
  // fills phys byte q = i*8192 + wid*1024 + lane*16 -> row = i*128+wid*16+(lane>>2),
  // in-row byte (lane&3)*16; pre-swizzled source kbyte = ((lane&3)^((lane>>3)&3))*16.
  int srow = wid * 16 + (lane >> 2);
  int scol = ((lane & 3) ^ ((lane >> 3) & 3)) * 16;
  const char* aSrc = (const char*)(Xhi + (size_t)(rowBase + srow) * DDIM) + scol;
  const char* bSrc = (const char*)(Yhi + (size_t)(colBase + srow) * DDIM) + scol;
  int ldsDst = wid * 1024;                        // wave-uniform; HW adds lane*16

  auto stage = [&](int ks, int s) {
    int ko = ks * 64;                             // 32 bf16 = 64 B per K-tile
    char* base = lds + s * 32768;
#pragma unroll
    for (int i = 0; i < 2; ++i) {
      gload16(aSrc + (size_t)(i * 128) * 2048 + ko, base + i * 8192 + ldsDst);
      gload16(bSrc + (size_t)(i * 128) * 2048 + ko, base + 16384 + i * 8192 + ldsDst);
    }
  };

  // per-thread read offsets (swizzle: rows 2-apart cycle 4 in-row 16B slots)
  int rdoff = (lk * 16) ^ (((lr >> 1) & 3) << 4);
  int aOff = (waveRow + lr) * 64 + rdoff;
  int bOff = 16384 + (waveCol + lr) * 64 + rdoff;

  // prologue: 3 tiles in flight (12 loads/thread)
  stage(0, 0); stage(1, 1); stage(2, 2);

  for (int ks = 0; ks < NT; ++ks) {
    int cur = ks & 3;
    // wait MY tile-ks loads retired; allow newer (ks+1, ks+2 = 8 loads) in flight
    if (ks < NT - 2)       asm volatile("s_waitcnt vmcnt(8)" ::: "memory");
    else if (ks == NT - 2) asm volatile("s_waitcnt vmcnt(4)" ::: "memory");
    else                   asm volatile("s_waitcnt vmcnt(0)" ::: "memory");
    __builtin_amdgcn_s_barrier();   // all waves: tile ks readable; slot ks-1 free
    __builtin_amdgcn_sched_barrier(0);

    if (ks + 3 < NT) stage(ks + 3, (ks + 3) & 3);  // into slot (ks-1)&3, now free

    const char* sBase = lds + cur * 32768;
    s16x8 af[8], bf[4];
#pragma unroll
    for (int m = 0; m < 8; ++m)
      af[m] = *(const s16x8*)(sBase + aOff + m * 1024);
#pragma unroll
    for (int n = 0; n < 4; ++n)
      bf[n] = *(const s16x8*)(sBase + bOff + n * 1024);
#pragma unroll
    for (int m = 0; m < 8; ++m)
#pragma unroll
      for (int n = 0; n < 4; ++n)
        acc[m][n] = __builtin_amdgcn_mfma_f32_16x16x32_bf16(af[m], bf[n], acc[m][n], 0, 0, 0);
    // no trailing barrier: next iteration's barrier certifies read-done
  }

  // fused epilogue: each 16x16 C-fragment == one (i,j) pair block
  float ns = nsp[0], sh = shp[0];
  float waveAcc = 0.f;
#pragma unroll
  for (int m = 0; m < 8; ++m) {
    int gr0 = rowBase + waveRow + m * 16;
    f32x4 x2v = *(const f32x4*)(x2 + gr0 + lk * 4);   // rows lk*4..lk*4+3
#pragma unroll
    for (int n = 0; n < 4; ++n) {
      int gc0 = colBase + waveCol + n * 16;
      bool diag = ((gr0 >> 4) == (gc0 >> 4));
      float y2c = y2[gc0 + lr];                        // col = lane&15
      float ts = 0.f;
#pragma unroll
      for (int r = 0; r < 4; ++r) {
        float sq = x2v[r] + y2c - 2.f * acc[m][n][r];
        sq = fmaxf(sq, 0.f);
        float dd = __fsqrt_rn(sq + DEPS);
        float l = sh - ns * dd;
        float a = diag ? (2.f * l) : (-2.f * l);
        ts += 1.f / (1.f + __expf(-a));                // sigmoid(2*m*l)
      }
#pragma unroll
      for (int off = 32; off >= 1; off >>= 1) ts += __shfl_xor(ts, off);
      waveAcc += (LOGKK - __logf(ts));
    }
  }
  // block-level reduce: 8 waves -> 1 atomic
  if (lane == 0) redBuf[wid] = waveAcc;
  __syncthreads();
  if (t == 0) {
    float bs = redBuf[0] + redBuf[1] + redBuf[2] + redBuf[3]
             + redBuf[4] + redBuf[5] + redBuf[6] + redBuf[7];
    atomicAdd(out, 2.f * bs);
  }
}

// ---------------- launch ----------------
extern "C" void kernel_launch(void* const* d_in, const int* in_sizes, int n_in,
                              void* d_out, int out_size, void* d_ws, size_t ws_size,
                              hipStream_t stream) {
  const float* img = (const float*)d_in[0];
  const float* cap = (const float*)d_in[1];
  const float* nsp = (const float*)d_in[4];
  const float* shp = (const float*)d_in[5];
  float* out = (float*)d_out;

  char* ws = (char*)d_ws;
  unsigned short* Xhi = (unsigned short*)(ws + (size_t)0);
  unsigned short* Yhi = (unsigned short*)(ws + (size_t)8 * 1024 * 1024);
  float* x2 = (float*)(ws + (size_t)16 * 1024 * 1024);
  float* y2 = (float*)(ws + (size_t)16 * 1024 * 1024 + 16384);
  // ws needed: 16 MiB + 32 KiB

  mcsc_prep<<<dim3(2048), dim3(256), 0, stream>>>(img, cap, Xhi, Yhi, x2, y2, out);
  mcsc_main<<<dim3(256), dim3(512), 0, stream>>>(Xhi, Yhi, x2, y2, nsp, shp, out);
}

// Round 12
// 135.134 us; speedup vs baseline: 1.0322x; 1.0322x over previous
//
#include <hip/hip_runtime.h>
#include <hip/hip_bf16.h>
#include <cstdint>

// MCSoftContrastiveLoss, MI355X (gfx950)
// loss = 2 * sum_{i,j} [ log(256) - log( sum_{k,l} sigmoid(2*m_ij*logit) ) ]
//   logit = shift - ns * sqrt(max(x2+y2-2xy,0)+1e-6),  m_ij = +1 if i==j else -1
// R10: 256x128 tile (per-XCD 4bm x 8bn region = 4 MB = L2-fit), 3-slot rolling
// LDS pipeline w/ counted vmcnt(6), 2 blocks/CU, 4 waves. Single bf16 GEMM
// (absmax 0.0 verified R4/R5/R8/R9).

using f32x4 = __attribute__((ext_vector_type(4))) float;
using s16x8 = __attribute__((ext_vector_type(8))) short;

#define DDIM   1024
#define BM     256
#define BN     128
#define BK     32
#define NT     32          // K-tiles = 1024/32
#define SLOT   24576       // A 16 KB + B 8 KB
#define LOGKK  5.5451774444795625f
#define DEPS   1e-6f

__device__ __forceinline__ void gload16(const void* g, void* l) {
  __builtin_amdgcn_global_load_lds((const __attribute__((address_space(1))) void*)g,
                                   (__attribute__((address_space(3))) void*)l, 16, 0, 0);
}

__device__ __forceinline__ unsigned short bf16_rne(float x) {
  uint32_t u = __builtin_bit_cast(uint32_t, x);
  uint32_t r = (u + 0x7FFFu + ((u >> 16) & 1u)) >> 16;
  return (unsigned short)r;
}

// -------- prep: 1 wave per row, no barriers, coalesced (R5-verified) --------
__global__ __launch_bounds__(256) void mcsc_prep(
    const float* __restrict__ img, const float* __restrict__ cap,
    unsigned short* __restrict__ Xhi, unsigned short* __restrict__ Yhi,
    float* __restrict__ x2, float* __restrict__ y2, float* __restrict__ out)
{
  int w = blockIdx.x * 4 + (threadIdx.x >> 6);   // 0..8191
  int lane = threadIdx.x & 63;
  int isY = w >> 12;
  int row = w & 4095;
  const float* src = (isY ? cap : img) + (size_t)row * DDIM;
  unsigned short* dst = (isY ? Yhi : Xhi) + (size_t)row * DDIM;

  float s = 0.f;
#pragma unroll
  for (int j = 0; j < 4; ++j) {
    int col = (j * 64 + lane) * 4;
    float4 v = *(const float4*)(src + col);
    const float* vp = (const float*)&v;
    unsigned short h[4];
#pragma unroll
    for (int e = 0; e < 4; ++e) { float x = vp[e]; s += x * x; h[e] = bf16_rne(x); }
    *(ushort4*)(dst + col) = make_ushort4(h[0], h[1], h[2], h[3]);
  }
#pragma unroll
  for (int off = 32; off >= 1; off >>= 1) s += __shfl_xor(s, off);
  if (lane == 0) (isY ? y2 : x2)[row] = s;
  if (w == 0 && lane == 0) out[0] = 0.f;
}

// -------- main: 256x128 NT-GEMM, 3-slot rolling pipeline, fused epilogue --------
__global__ __launch_bounds__(256, 2) void mcsc_main(
    const unsigned short* __restrict__ Xhi, const unsigned short* __restrict__ Yhi,
    const float* __restrict__ x2, const float* __restrict__ y2,
    const float* __restrict__ nsp, const float* __restrict__ shp,
    float* __restrict__ out)
{
  // 3 slots x 24 KB: [A: 256x32 bf16 (16 KB) | B: 128x32 bf16 (8 KB)]
  // rows are 64 B; swizzle: phys_inrow16 = logical16 ^ ((row>>1) & 3)
  __shared__ __align__(16) char lds[3 * SLOT];
  __shared__ float redBuf[4];

  // Region-mapped XCD swizzle: tile grid 16(bm) x 32(bn); 16 regions of 4x8.
  // XCD x runs region x first (32 blocks = 32 CUs), then region x+8.
  // Per-XCD concurrent footprint: 4x512K (A) + 8x256K (B) = 4 MB = L2.
  int bid = blockIdx.x;
  int xcd = bid & 7, k = bid >> 3;               // k in [0,64)
  int region = xcd + 8 * (k >> 5);               // [0,16)
  int idx = k & 31;
  int bm = (region >> 2) * 4 + (idx >> 3);       // [0,16)
  int bn = (region & 3) * 8 + (idx & 7);         // [0,32)
  int rowBase = bm * BM, colBase = bn * BN;

  int t = threadIdx.x;
  int wid = t >> 6, lane = t & 63;
  int lr = lane & 15, lk = lane >> 4;
  int wr = wid >> 1, wc = wid & 1;               // 2M x 2N waves
  int waveRow = wr * 128, waveCol = wc * 64;

  f32x4 acc[8][4] = {};

  // Staging: A 4 instr/thread, B 2 instr/thread (16 B each).
  // Instr i, thread t fills phys byte q = i*4096 + t*16 ->
  // row = i*64 + (t>>2), in-row 16B slot (t&3); pre-swizzled source slot
  // (t&3) ^ ((t>>3)&3)  [since (row>>1)&3 == (t>>3)&3, i*64 vanishing mod 4].
  int srow = t >> 2;
  int scol = ((t & 3) ^ ((t >> 3) & 3)) * 16;
  const char* aSrc = (const char*)(Xhi + (size_t)(rowBase + srow) * DDIM) + scol;
  const char* bSrc = (const char*)(Yhi + (size_t)(colBase + srow) * DDIM) + scol;
  int ldsDst = wid * 1024;                       // wave-uniform; HW adds lane*16

  auto stage = [&](int ks, int s) {
    int ko = ks * 64;                            // 32 bf16 = 64 B per K-tile
    char* base = lds + s * SLOT;
#pragma unroll
    for (int i = 0; i < 4; ++i)
      gload16(aSrc + (size_t)(i * 64) * 2048 + ko, base + i * 4096 + ldsDst);
#pragma unroll
    for (int i = 0; i < 2; ++i)
      gload16(bSrc + (size_t)(i * 64) * 2048 + ko, base + 16384 + i * 4096 + ldsDst);
  };

  // per-thread read offsets (rows 2-apart cycle the 4 in-row 16B slots)
  int rdoff = (lk * 16) ^ (((lr >> 1) & 3) << 4);
  int aOff = (waveRow + lr) * 64 + rdoff;
  int bOff = 16384 + (waveCol + lr) * 64 + rdoff;

  // prologue: 2 tiles in flight (12 loads/thread)
  stage(0, 0); stage(1, 1);

  for (int ks = 0; ks < NT; ++ks) {
    int cur = ks % 3;
    // wait tile-ks loads retired; allow tile ks+1 (6 loads) in flight
    if (ks < NT - 1) asm volatile("s_waitcnt vmcnt(6)" ::: "memory");
    else             asm volatile("s_waitcnt vmcnt(0)" ::: "memory");
    __builtin_amdgcn_s_barrier();   // tile ks readable; slot (ks-1)%3 free
    __builtin_amdgcn_sched_barrier(0);

    if (ks + 2 < NT) stage(ks + 2, (ks + 2) % 3);

    const char* sBase = lds + cur * SLOT;
    s16x8 af[8], bf[4];
#pragma unroll
    for (int m = 0; m < 8; ++m)
      af[m] = *(const s16x8*)(sBase + aOff + m * 1024);
#pragma unroll
    for (int n = 0; n < 4; ++n)
      bf[n] = *(const s16x8*)(sBase + bOff + n * 1024);
#pragma unroll
    for (int m = 0; m < 8; ++m)
#pragma unroll
      for (int n = 0; n < 4; ++n)
        acc[m][n] = __builtin_amdgcn_mfma_f32_16x16x32_bf16(af[m], bf[n], acc[m][n], 0, 0, 0);
    // no trailing barrier: next iteration's barrier certifies read-done
  }

  // fused epilogue: each 16x16 C-fragment == one (i,j) pair block
  float ns = nsp[0], sh = shp[0];
  float waveAcc = 0.f;
#pragma unroll
  for (int m = 0; m < 8; ++m) {
    int gr0 = rowBase + waveRow + m * 16;
    f32x4 x2v = *(const f32x4*)(x2 + gr0 + lk * 4);   // rows lk*4..lk*4+3
#pragma unroll
    for (int n = 0; n < 4; ++n) {
      int gc0 = colBase + waveCol + n * 16;
      bool diag = ((gr0 >> 4) == (gc0 >> 4));
      float y2c = y2[gc0 + lr];                        // col = lane&15
      float ts = 0.f;
#pragma unroll
      for (int r = 0; r < 4; ++r) {
        float sq = x2v[r] + y2c - 2.f * acc[m][n][r];
        sq = fmaxf(sq, 0.f);
        float dd = __fsqrt_rn(sq + DEPS);
        float l = sh - ns * dd;
        float a = diag ? (2.f * l) : (-2.f * l);
        ts += 1.f / (1.f + __expf(-a));                // sigmoid(2*m*l)
      }
#pragma unroll
      for (int off = 32; off >= 1; off >>= 1) ts += __shfl_xor(ts, off);
      waveAcc += (LOGKK - __logf(ts));
    }
  }
  // block-level reduce: 4 waves -> 1 atomic
  if (lane == 0) redBuf[wid] = waveAcc;
  __syncthreads();
  if (t == 0) {
    float bs = redBuf[0] + redBuf[1] + redBuf[2] + redBuf[3];
    atomicAdd(out, 2.f * bs);
  }
}

// ---------------- launch ----------------
extern "C" void kernel_launch(void* const* d_in, const int* in_sizes, int n_in,
                              void* d_out, int out_size, void* d_ws, size_t ws_size,
                              hipStream_t stream) {
  const float* img = (const float*)d_in[0];
  const float* cap = (const float*)d_in[1];
  const float* nsp = (const float*)d_in[4];
  const float* shp = (const float*)d_in[5];
  float* out = (float*)d_out;

  char* ws = (char*)d_ws;
  unsigned short* Xhi = (unsigned short*)(ws + (size_t)0);
  unsigned short* Yhi = (unsigned short*)(ws + (size_t)8 * 1024 * 1024);
  float* x2 = (float*)(ws + (size_t)16 * 1024 * 1024);
  float* y2 = (float*)(ws + (size_t)16 * 1024 * 1024 + 16384);
  // ws needed: 16 MiB + 32 KiB

  mcsc_prep<<<dim3(2048), dim3(256), 0, stream>>>(img, cap, Xhi, Yhi, x2, y2, out);
  mcsc_main<<<dim3(512), dim3(256), 0, stream>>>(Xhi, Yhi, x2, y2, nsp, shp, out);
}

// Round 13
// 132.257 us; speedup vs baseline: 1.0546x; 1.0218x over previous
//
#include <hip/hip_runtime.h>
#include <hip/hip_bf16.h>
#include <cstdint>

// MCSoftContrastiveLoss, MI355X (gfx950)
// loss = 2 * sum_{i,j} [ log(256) - log( sum_{k,l} sigmoid(2*m_ij*logit) ) ]
//   logit = shift - ns * sqrt(max(x2+y2-2xy,0)+1e-6),  m_ij = +1 if i==j else -1
// R13: R9 geometry (256x256, BK=32, 4-slot rolling, counted vmcnt) + fine
// 2-sub-phase interleave per K-tile {ds_read, stage-half, bar, lgkm0, setprio,
// 16 MFMA, bar} = T3+T4+T5 stack. Single bf16 GEMM (absmax 0.0 R4/R5/R8/R9/R12).

using f32x4 = __attribute__((ext_vector_type(4))) float;
using s16x8 = __attribute__((ext_vector_type(8))) short;

#define DDIM   1024
#define BM     256
#define BN     256
#define BK     32
#define NT     32          // K-tiles = 1024/32
#define LOGKK  5.5451774444795625f
#define DEPS   1e-6f

__device__ __forceinline__ void gload16(const void* g, void* l) {
  __builtin_amdgcn_global_load_lds((const __attribute__((address_space(1))) void*)g,
                                   (__attribute__((address_space(3))) void*)l, 16, 0, 0);
}

__device__ __forceinline__ unsigned short bf16_rne(float x) {
  uint32_t u = __builtin_bit_cast(uint32_t, x);
  uint32_t r = (u + 0x7FFFu + ((u >> 16) & 1u)) >> 16;
  return (unsigned short)r;
}

// -------- prep: 1 wave per row, no barriers, coalesced (R5-verified) --------
__global__ __launch_bounds__(256) void mcsc_prep(
    const float* __restrict__ img, const float* __restrict__ cap,
    unsigned short* __restrict__ Xhi, unsigned short* __restrict__ Yhi,
    float* __restrict__ x2, float* __restrict__ y2, float* __restrict__ out)
{
  int w = blockIdx.x * 4 + (threadIdx.x >> 6);   // 0..8191
  int lane = threadIdx.x & 63;
  int isY = w >> 12;
  int row = w & 4095;
  const float* src = (isY ? cap : img) + (size_t)row * DDIM;
  unsigned short* dst = (isY ? Yhi : Xhi) + (size_t)row * DDIM;

  float s = 0.f;
#pragma unroll
  for (int j = 0; j < 4; ++j) {
    int col = (j * 64 + lane) * 4;
    float4 v = *(const float4*)(src + col);
    const float* vp = (const float*)&v;
    unsigned short h[4];
#pragma unroll
    for (int e = 0; e < 4; ++e) { float x = vp[e]; s += x * x; h[e] = bf16_rne(x); }
    *(ushort4*)(dst + col) = make_ushort4(h[0], h[1], h[2], h[3]);
  }
#pragma unroll
  for (int off = 32; off >= 1; off >>= 1) s += __shfl_xor(s, off);
  if (lane == 0) (isY ? y2 : x2)[row] = s;
  if (w == 0 && lane == 0) out[0] = 0.f;
}

// -------- main: 256x256, 4-slot rolling, 2 fine phases/K-tile, fused epilogue ----
__global__ __launch_bounds__(512, 2) void mcsc_main(
    const unsigned short* __restrict__ Xhi, const unsigned short* __restrict__ Yhi,
    const float* __restrict__ x2, const float* __restrict__ y2,
    const float* __restrict__ nsp, const float* __restrict__ shp,
    float* __restrict__ out)
{
  // 4 slots x 32 KB: [A: 256x32 bf16 (16 KB) | B: 256x32 bf16 (16 KB)]
  // rows 64 B; swizzle: phys_inrow16 = logical16 ^ ((row>>1) & 3)   (R9-verified)
  __shared__ __align__(16) char lds[4 * 32768];
  __shared__ float redBuf[8];

  // XCD-bijective swizzle (256 % 8 == 0)   (R9-verified)
  int bid = blockIdx.x;
  int wg = (bid & 7) * 32 + (bid >> 3);
  int bm = wg >> 4, bn = wg & 15;                 // 16 x 16 tile grid
  int rowBase = bm * BM, colBase = bn * BN;

  int t = threadIdx.x;
  int wid = t >> 6, lane = t & 63;
  int lr = lane & 15, lk = lane >> 4;
  int wr = wid >> 2, wc = wid & 3;                // 2M x 4N waves
  int waveRow = wr * 128, waveCol = wc * 64;

  f32x4 acc[8][4] = {};

  // Staging (R9-verified formulas): per tile 4 gload16/thread (A,B x 2 halves).
  int srow = wid * 16 + (lane >> 2);              // [0,128)
  int scol = ((lane & 3) ^ ((lane >> 3) & 3)) * 16;
  const char* aSrc = (const char*)(Xhi + (size_t)(rowBase + srow) * DDIM) + scol;
  const char* bSrc = (const char*)(Yhi + (size_t)(colBase + srow) * DDIM) + scol;
  int ldsDst = wid * 1024;                        // wave-uniform; HW adds lane*16

  // stage one half (h=0: rows 0-127, h=1: rows 128-255) of tile ks into slot s
  auto stage_half = [&](int ks, int s, int h) {
    int ko = ks * 64;                             // 32 bf16 = 64 B per K-tile
    char* base = lds + s * 32768;
    gload16(aSrc + (size_t)(h * 128) * 2048 + ko, base + h * 8192 + ldsDst);
    gload16(bSrc + (size_t)(h * 128) * 2048 + ko, base + 16384 + h * 8192 + ldsDst);
  };

  // per-thread read offsets (R9-verified)
  int rdoff = (lk * 16) ^ (((lr >> 1) & 3) << 4);
  int aOff = (waveRow + lr) * 64 + rdoff;
  int bOff = 16384 + (waveCol + lr) * 64 + rdoff;

  // prologue: tiles 0,1,2 in flight (12 loads/thread)
  stage_half(0, 0, 0); stage_half(0, 0, 1);
  stage_half(1, 1, 0); stage_half(1, 1, 1);
  stage_half(2, 2, 0); stage_half(2, 2, 1);
  asm volatile("s_waitcnt vmcnt(8)" ::: "memory");  // tile 0 landed; 1,2 in flight
  __builtin_amdgcn_s_barrier();                      // cert: tile 0 readable

  for (int ks = 0; ks < NT; ++ks) {
    int cur = ks & 3;
    const char* sBase = lds + cur * 32768;
    bool more = (ks + 3 < NT);
    int nslot = (ks + 3) & 3;

    // ---- phase 0: a[0..3], b[0..3]; MFMA m=0..3 ----
    s16x8 af[4], bf[4];
#pragma unroll
    for (int m = 0; m < 4; ++m)
      af[m] = *(const s16x8*)(sBase + aOff + m * 1024);
#pragma unroll
    for (int n = 0; n < 4; ++n)
      bf[n] = *(const s16x8*)(sBase + bOff + n * 1024);
    if (more) stage_half(ks + 3, nslot, 0);
    __builtin_amdgcn_s_barrier();
    asm volatile("s_waitcnt lgkmcnt(0)" ::: "memory");
    __builtin_amdgcn_sched_barrier(0);
    __builtin_amdgcn_s_setprio(1);
#pragma unroll
    for (int m = 0; m < 4; ++m)
#pragma unroll
      for (int n = 0; n < 4; ++n)
        acc[m][n] = __builtin_amdgcn_mfma_f32_16x16x32_bf16(af[m], bf[n], acc[m][n], 0, 0, 0);
    __builtin_amdgcn_s_setprio(0);
    __builtin_amdgcn_s_barrier();

    // ---- phase 1: a[4..7]; MFMA m=4..7 (reuses bf) ----
    s16x8 ag[4];
#pragma unroll
    for (int m = 0; m < 4; ++m)
      ag[m] = *(const s16x8*)(sBase + aOff + (m + 4) * 1024);
    if (more) stage_half(ks + 3, nslot, 1);
    // cert for tile ks+1: counted, never 0 until the tail
    if (ks < 29)       asm volatile("s_waitcnt vmcnt(8)" ::: "memory");
    else if (ks == 29) asm volatile("s_waitcnt vmcnt(4)" ::: "memory");
    else if (ks == 30) asm volatile("s_waitcnt vmcnt(0)" ::: "memory");
    __builtin_amdgcn_s_barrier();
    asm volatile("s_waitcnt lgkmcnt(0)" ::: "memory");
    __builtin_amdgcn_sched_barrier(0);
    __builtin_amdgcn_s_setprio(1);
#pragma unroll
    for (int m = 0; m < 4; ++m)
#pragma unroll
      for (int n = 0; n < 4; ++n)
        acc[m + 4][n] = __builtin_amdgcn_mfma_f32_16x16x32_bf16(ag[m], bf[n], acc[m + 4][n], 0, 0, 0);
    __builtin_amdgcn_s_setprio(0);
    __builtin_amdgcn_s_barrier();   // == cert: tile ks+1 readable, slot ks free
  }

  // fused epilogue: each 16x16 C-fragment == one (i,j) pair block
  float ns = nsp[0], sh = shp[0];
  float waveAcc = 0.f;
#pragma unroll
  for (int m = 0; m < 8; ++m) {
    int gr0 = rowBase + waveRow + m * 16;
    f32x4 x2v = *(const f32x4*)(x2 + gr0 + lk * 4);   // rows lk*4..lk*4+3
#pragma unroll
    for (int n = 0; n < 4; ++n) {
      int gc0 = colBase + waveCol + n * 16;
      bool diag = ((gr0 >> 4) == (gc0 >> 4));
      float y2c = y2[gc0 + lr];                        // col = lane&15
      float ts = 0.f;
#pragma unroll
      for (int r = 0; r < 4; ++r) {
        float sq = x2v[r] + y2c - 2.f * acc[m][n][r];
        sq = fmaxf(sq, 0.f);
        float dd = __fsqrt_rn(sq + DEPS);
        float l = sh - ns * dd;
        float a = diag ? (2.f * l) : (-2.f * l);
        ts += 1.f / (1.f + __expf(-a));                // sigmoid(2*m*l)
      }
#pragma unroll
      for (int off = 32; off >= 1; off >>= 1) ts += __shfl_xor(ts, off);
      waveAcc += (LOGKK - __logf(ts));
    }
  }
  // block-level reduce: 8 waves -> 1 atomic
  if (lane == 0) redBuf[wid] = waveAcc;
  __syncthreads();
  if (t == 0) {
    float bs = redBuf[0] + redBuf[1] + redBuf[2] + redBuf[3]
             + redBuf[4] + redBuf[5] + redBuf[6] + redBuf[7];
    atomicAdd(out, 2.f * bs);
  }
}

// ---------------- launch ----------------
extern "C" void kernel_launch(void* const* d_in, const int* in_sizes, int n_in,
                              void* d_out, int out_size, void* d_ws, size_t ws_size,
                              hipStream_t stream) {
  const float* img = (const float*)d_in[0];
  const float* cap = (const float*)d_in[1];
  const float* nsp = (const float*)d_in[4];
  const float* shp = (const float*)d_in[5];
  float* out = (float*)d_out;

  char* ws = (char*)d_ws;
  unsigned short* Xhi = (unsigned short*)(ws + (size_t)0);
  unsigned short* Yhi = (unsigned short*)(ws + (size_t)8 * 1024 * 1024);
  float* x2 = (float*)(ws + (size_t)16 * 1024 * 1024);
  float* y2 = (float*)(ws + (size_t)16 * 1024 * 1024 + 16384);
  // ws needed: 16 MiB + 32 KiB

  mcsc_prep<<<dim3(2048), dim3(256), 0, stream>>>(img, cap, Xhi, Yhi, x2, y2, out);
  mcsc_main<<<dim3(256), dim3(512), 0, stream>>>(Xhi, Yhi, x2, y2, nsp, shp, out);
}